// Round 12
// baseline (34.654 us; speedup 1.0000x reference)
//
#include <hip/hip_runtime.h>
#include <hip/hip_bf16.h>

#define NH 32          // heads
#define NV 1537        // edge_enc_w rows
#define ND 20          // MULTI_HOP_MAX_DIST
#define NB 16          // batch
#define NN 64          // nodes

#define ENC_U32 (NV*8)                   // 12296 u32 (fp8 enc, 32 B/row)
#define WDT_U32 (ND*NH*NH/2)             // 10240 u32 (bf16 WdT, [d][h][kp])

// LDS layout (bytes)
#define LDS_ENC  0
#define LDS_WDT  49184                   // = ENC_U32*4
#define LDS_SDX  90144                   // = LDS_WDT + WDT_U32*4
#define LDS_SPOS 131104                  // = LDS_SDX + 256*80*2
#define MAIN_LDS 132128                  // + 256*4

typedef unsigned int   u32;
typedef unsigned short u16;
typedef __attribute__((ext_vector_type(2))) float        f32x2;
typedef __attribute__((ext_vector_type(4))) float        f32x4;
typedef __attribute__((ext_vector_type(2))) unsigned int u32x2;
typedef __attribute__((ext_vector_type(4))) int          v4i;
typedef __attribute__((ext_vector_type(8))) short        bf16x8_t;

// ---- fp8 e4m3 helpers (proven R7-R11) ----
__device__ __forceinline__ f32x2 fp8x2_to_f32(u32 u) {
#if __has_builtin(__builtin_amdgcn_cvt_pk_f32_fp8)
    return __builtin_amdgcn_cvt_pk_f32_fp8(u, false);
#else
    f32x2 r;
    asm("v_cvt_pk_f32_fp8 %0, %1" : "=v"(r) : "v"(u));
    return r;
#endif
}
__device__ __forceinline__ u32 f32x4_to_fp8(float a0, float a1, float a2, float a3) {
#if __has_builtin(__builtin_amdgcn_cvt_pk_fp8_f32)
    u32 u = __builtin_amdgcn_cvt_pk_fp8_f32(a0, a1, 0u, false);
    u     = __builtin_amdgcn_cvt_pk_fp8_f32(a2, a3, u,  true);
    return u;
#else
    u32 lo, hi;
    asm("v_cvt_pk_fp8_f32 %0, %1, %2" : "=v"(lo) : "v"(a0), "v"(a1));
    asm("v_cvt_pk_fp8_f32 %0, %1, %2" : "=v"(hi) : "v"(a2), "v"(a3));
    return (lo & 0xffffu) | (hi << 16);
#endif
}
__device__ __forceinline__ u32 pk_bf16(float lo, float hi) {
    u32 r;
    asm("v_cvt_pk_bf16_f32 %0, %1, %2" : "=v"(r) : "v"(lo), "v"(hi));
    return r;
}

// ---------------- Single fused kernel ----------------
// 256 blocks x 512 thr (8 waves), 1 block/CU, 132KB LDS.
// Stage phase (one barrier): enc f32->fp8 LDS (49KB), Wd->bf16^T LDS (40KB),
// edge indices -> u16 LDS, spos -> LDS, border writes (258/block).
// Compute (R11-verified): per d, A = sum of 3 fp8 enc rows -> bf16,
// 2x mfma_f32_16x16x32_bf16. Epilogue: comb in LDS, 256B-coalesced writes.
__global__ void __launch_bounds__(512, 1)
fused_kernel(const float* __restrict__ ab,      // (B,65,65)
             const int*   __restrict__ spos,    // (B,64,64)
             const int*   __restrict__ eidx,    // (B,64,64,20,3)
             const float* __restrict__ mask2d,  // (B,)
             const float* __restrict__ spw,     // (512,32)
             const float* __restrict__ tokw,    // (32,)
             const float* __restrict__ enc,     // (1537,32)
             const float* __restrict__ wdis,    // (20,32,32) of (131072,1)
             float*       __restrict__ out) {   // (B,32,65,65)
    extern __shared__ __align__(16) char dyn[];
    u32* enc8  = (u32*)(dyn + LDS_ENC);
    u32* wdt   = (u32*)(dyn + LDS_WDT);
    u16* sdx   = (u16*)(dyn + LDS_SDX);        // [256 cells][20 d][4]
    int* sposL = (int*)(dyn + LDS_SPOS);

    int tid = threadIdx.x, blk = blockIdx.x;
    int b = blk >> 4, i0 = (blk & 15) << 2;

    // (a) enc f32 -> fp8 (x256) into LDS: 24 iters, coalesced 16B loads
    for (int p = tid; p < ENC_U32; p += 512) {
        float4 e = *(const float4*)(enc + (size_t)p * 4);
        enc8[p] = f32x4_to_fp8(e.x * 256.f, e.y * 256.f,
                               e.z * 256.f, e.w * 256.f);
    }
    // (b) Wd -> bf16^T LDS [d][h][kp]: linear LDS writes, strided L2-hot reads
    for (int o = tid; o < WDT_U32; o += 512) {
        int d = o >> 9, rem = o & 511;
        int h = rem >> 4, kp = rem & 15;
        const float* ws = wdis + d * 1024 + h;
        wdt[o] = pk_bf16(ws[(2 * kp) * 32], ws[(2 * kp + 1) * 32]);
    }
    // (c) edge indices: 256 cells x 60 -> sdx[cell][d][4] u16
    const v4i* ep4 = (const v4i*)(eidx + (size_t)blk * 256 * 60);
    for (int t = tid; t < 3840; t += 512) {
        v4i q = __builtin_nontemporal_load(ep4 + t);
        int base = t * 4;
#pragma unroll
        for (int c = 0; c < 4; ++c) {
            int f2 = base + c;
            int cell = f2 / 60, pos = f2 - cell * 60;
            int d = pos / 3, f = pos - d * 3;
            int val = (c == 0) ? q.x : (c == 1) ? q.y : (c == 2) ? q.z : q.w;
            sdx[cell * 80 + d * 4 + f] = (u16)val;
        }
    }
    // (d) spos
    if (tid < 256) sposL[tid] = spos[blk * 256 + tid];
    // (e) borders: batch b has 4128 border elems; this block does slice blk&15
    if (tid < 258) {
        int t = (blk & 15) * 258 + tid;        // 16*258 = 4128 exactly
        if (t < 2080) {                        // row 0, h x 65 j
            int h = t / 65, j = t - h * 65;
            __builtin_nontemporal_store(2.0f * ab[b * 4225 + j] + tokw[h],
                &out[(((size_t)b * NH + h) * 65 + 0) * 65 + j]);
        } else {                               // col 0, i >= 1
            int t2 = t - 2080;
            int h = t2 >> 6, i = (t2 & 63) + 1;
            __builtin_nontemporal_store(2.0f * ab[b * 4225 + i * 65] + tokw[h],
                &out[(((size_t)b * NH + h) * 65 + i) * 65 + 0]);
        }
    }
    __syncthreads();

    // --- compute (R11-verified): wave wv owns tiles 2wv, 2wv+1 ---
    int wv = tid >> 6, l = tid & 63;
    int c16 = l & 15, g = l >> 4;              // A/B row|col, k-group
    int t0 = wv * 2;

    const char* encB = (const char*)enc8 + g * 8;
    const char* wdB1 = (const char*)wdt + c16 * 64 + g * 16;
    const char* wdB2 = (const char*)wdt + (c16 + 16) * 64 + g * 16;
    const u16* sdx0 = sdx + (t0 * 16 + c16) * 80;
    const u16* sdx1 = sdx + ((t0 + 1) * 16 + c16) * 80;

    f32x4 acc[2][2] = {};                      // [tile][head-half]

    for (int d = 0; d < ND; ++d) {
        bf16x8_t b1 = *(const bf16x8_t*)(wdB1 + d * 2048);
        bf16x8_t b2 = *(const bf16x8_t*)(wdB2 + d * 2048);
#pragma unroll
        for (int t = 0; t < 2; ++t) {
            const u16* sx = t ? sdx1 : sdx0;
            ushort4 q = *(const ushort4*)(sx + d * 4);
            u32x2 e0 = *(const u32x2*)(encB + ((u32)q.x << 5));
            u32x2 e1 = *(const u32x2*)(encB + ((u32)q.y << 5));
            u32x2 e2 = *(const u32x2*)(encB + ((u32)q.z << 5));
            f32x2 s0 = fp8x2_to_f32(e0.x) + fp8x2_to_f32(e1.x) + fp8x2_to_f32(e2.x);
            f32x2 s1 = fp8x2_to_f32(e0.x >> 16) + fp8x2_to_f32(e1.x >> 16)
                     + fp8x2_to_f32(e2.x >> 16);
            f32x2 s2 = fp8x2_to_f32(e0.y) + fp8x2_to_f32(e1.y) + fp8x2_to_f32(e2.y);
            f32x2 s3 = fp8x2_to_f32(e0.y >> 16) + fp8x2_to_f32(e1.y >> 16)
                     + fp8x2_to_f32(e2.y >> 16);
            union { u32 w[4]; bf16x8_t v; } au;
            au.w[0] = pk_bf16(s0.x, s0.y);
            au.w[1] = pk_bf16(s1.x, s1.y);
            au.w[2] = pk_bf16(s2.x, s2.y);
            au.w[3] = pk_bf16(s3.x, s3.y);
            acc[t][0] = __builtin_amdgcn_mfma_f32_16x16x32_bf16(au.v, b1, acc[t][0], 0, 0, 0);
            acc[t][1] = __builtin_amdgcn_mfma_f32_16x16x32_bf16(au.v, b2, acc[t][1], 0, 0, 0);
        }
    }

    __syncthreads();                           // sdx dead; alias comb over it
    float* comb = (float*)(dyn + LDS_SDX);     // [256 cells][33]
    float m = mask2d[b];
#pragma unroll
    for (int t = 0; t < 2; ++t) {
#pragma unroll
        for (int r = 0; r < 4; ++r) {
            int cell = (t0 + t) * 16 + g * 4 + r;   // D: row=(l>>4)*4+r
            int s = sposL[cell];
            int sp = (s == 0) ? 1 : s;
            sp = (sp > 1) ? sp - 1 : sp;
            sp = (sp > ND) ? ND : sp;
            float esc = m / (768.0f * (float)sp);   // /3sp and /256 fp8 scale
            float spbL = spw[s * NH + c16];          // D: col=l&15 -> head
            float spbH = spw[s * NH + c16 + 16];
            comb[cell * 33 + c16]      = spbL * m + acc[t][0][r] * esc;
            comb[cell * 33 + c16 + 16] = spbH * m + acc[t][1][r] * esc;
        }
    }
    __syncthreads();

    // --- write out: 4 i-rows x 32 h x 64 j, 256B-coalesced over j ---
#pragma unroll
    for (int w = 0; w < 16; ++w) {
        int idx = w * 512 + tid;
        int j = idx & 63, h = (idx >> 6) & 31, r = idx >> 11;
        float av = ab[(b * 65 + i0 + r + 1) * 65 + (j + 1)];
        __builtin_nontemporal_store(2.0f * av + comb[(r * 64 + j) * 33 + h],
            &out[(((size_t)b * NH + h) * 65 + i0 + r + 1) * 65 + (j + 1)]);
    }
}

extern "C" void kernel_launch(void* const* d_in, const int* in_sizes, int n_in,
                              void* d_out, int out_size, void* d_ws, size_t ws_size,
                              hipStream_t stream) {
    const float* attn_bias   = (const float*)d_in[0];
    const int*   spatial_pos = (const int*)  d_in[1];
    // d_in[2] = x (unused), d_in[4] = attn_edge_type (unused)
    const int*   edge_input  = (const int*)  d_in[3];
    const float* mask_2d     = (const float*)d_in[5];
    const float* edge_enc_w  = (const float*)d_in[6];
    const float* edge_dis_w  = (const float*)d_in[7];
    const float* spatial_w   = (const float*)d_in[8];
    const float* token_w     = (const float*)d_in[9];
    float* out = (float*)d_out;

    // one fused dispatch; d_ws unused
    fused_kernel<<<256, 512, MAIN_LDS, stream>>>(attn_bias, spatial_pos, edge_input,
                                                 mask_2d, spatial_w, token_w,
                                                 edge_enc_w, edge_dis_w, out);
}